// Round 2
// baseline (1012.554 us; speedup 1.0000x reference)
//
#include <hip/hip_runtime.h>

#define NROWS 16384
#define DDIM 64
#define KCB 8192
#define CIN 512
#define OUTC 512
#define OUT_MAIN 8388608

// scratch offsets within d_out (in floats)
#define OFF_ZT 0          // zt[64][16384]
#define OFF_ET 1048576    // et[64][8192]
#define OFF_E2 1572864    // e2[8192]
#define OFF_PMV 1581056   // pmv[8][16384]
#define OFF_PMI 1712128   // pmi[8][16384] (ints)

// ---------------- K1: encoder 1x1 conv, writes z TRANSPOSED zt[d][n]
// grid 1024: bh = bid>>1 (b*32+h), dh = bid&1 (d-half)
__global__ __launch_bounds__(256) void k_enc(const float* __restrict__ x,
                                             const float* __restrict__ w_in,
                                             const float* __restrict__ b_in,
                                             float* __restrict__ zt) {
  __shared__ float Wt[128][36];  // [c][dd], dd in 0..31
  const int bid = blockIdx.x;
  const int bh = bid >> 1, dh = bid & 1;
  const int b = bh >> 5, h = bh & 31;
  const int d0 = dh * 32;
  const int t = threadIdx.x;
  const int w = t & 31, dg = t >> 5;  // dg 0..7 -> d = d0+dg*4..+3
  float acc[4];
#pragma unroll
  for (int j = 0; j < 4; ++j) acc[j] = b_in[d0 + dg * 4 + j];
  const float* xb = x + ((size_t)b * CIN * 1024) + h * 32 + w;
  for (int c0 = 0; c0 < CIN; c0 += 128) {
    __syncthreads();
#pragma unroll
    for (int i = 0; i < 16; ++i) {
      int e = t + 256 * i;
      int cc = e & 127, dd = e >> 7;
      Wt[cc][dd] = w_in[(size_t)(d0 + dd) * CIN + c0 + cc];
    }
    __syncthreads();
#pragma unroll 8
    for (int c = 0; c < 128; ++c) {
      float xv = xb[(size_t)(c0 + c) * 1024];
      const float4 wv = *(const float4*)&Wt[c][dg * 4];
      acc[0] = fmaf(xv, wv.x, acc[0]);
      acc[1] = fmaf(xv, wv.y, acc[1]);
      acc[2] = fmaf(xv, wv.z, acc[2]);
      acc[3] = fmaf(xv, wv.w, acc[3]);
    }
  }
  const int n = bh * 32 + w;
#pragma unroll
  for (int j = 0; j < 4; ++j) zt[(size_t)(d0 + dg * 4 + j) * NROWS + n] = acc[j];
}

// ---------------- K2: transpose emb -> et[d][k], and e2[k] = ||emb[k]||^2
__global__ __launch_bounds__(256) void k_prep(const float* __restrict__ emb,
                                              float* __restrict__ et,
                                              float* __restrict__ e2) {
  __shared__ float Es[DDIM][68];  // [d][k-local]
  const int k0 = blockIdx.x * 64;
  const int t = threadIdx.x;
  {
    const int dd = t & 63, kl4 = t >> 6;
#pragma unroll
    for (int i = 0; i < 16; ++i) {
      int kl = kl4 + 4 * i;
      Es[dd][kl] = emb[(size_t)(k0 + kl) * DDIM + dd];
    }
  }
  __syncthreads();
  if (t < 64) {
    float s = 0.f;
#pragma unroll
    for (int d = 0; d < 64; ++d) s = fmaf(Es[d][t], Es[d][t], s);
    e2[k0 + t] = s;
  }
  const int dd = t >> 2;
#pragma unroll
  for (int i = 0; i < 4; ++i) {
    int ch = (t & 3) + 4 * i;  // 0..15 float4 chunks of the 64-k row
    float4 v = *(const float4*)&Es[dd][ch * 4];
    *(float4*)&et[(size_t)dd * KCB + k0 + ch * 4] = v;
  }
}

// ---------------- K3: fused distance-GEMM + argmin
// grid 1024: rt = bid&127 (128-row tile), kh = bid>>7 (1024-k range)
// block tile 128 rows x 128 ks, d-chunked by 16, double-buffered LDS,
// thread tile 8x8 (split 4+4 at stride 64 for conflict-free LDS reads)
__global__ __launch_bounds__(256, 4) void k_argmin(const float* __restrict__ zt,
                                                   const float* __restrict__ et,
                                                   const float* __restrict__ e2,
                                                   float* __restrict__ pmv,
                                                   int* __restrict__ pmi) {
  __shared__ float Zs[2][2048];   // [buf][16 d][128 r]
  __shared__ float Es2[2][2048];  // [buf][16 d][128 k]
  const int bid = blockIdx.x;
  const int rt = bid & 127, kh = bid >> 7;
  const int r0 = rt * 128;
  const int k0base = kh * 1024;
  const int t = threadIdx.x;
  const int tx4 = (t & 15) * 4;
  const int ty4 = ((t >> 4) & 15) * 4;
  const int l = t & 63, ws = t >> 6;

  float acc[2][2][4][4];
  float mv[2][4];
  int mi[2][4];
#pragma unroll
  for (int zh = 0; zh < 2; ++zh)
#pragma unroll
    for (int i = 0; i < 4; ++i) { mv[zh][i] = 3.4028235e38f; mi[zh][i] = 0; }

  auto stage = [&](int g, int bi) {
    const int kt = g >> 2, dc = g & 3;
    const int d0 = dc * 16;
    const int kb = k0base + kt * 128;
#pragma unroll
    for (int jj = 0; jj < 2; ++jj) {
      const int j = 2 * ws + jj;          // 0..7 -> covers d-rows 2j, 2j+1
      const int drow = 2 * j + (l >> 5);  // 0..15
      const int col = (l & 31) * 4;
      const float* gz = zt + (size_t)(d0 + drow) * NROWS + r0 + col;
      const float* ge = et + (size_t)(d0 + drow) * KCB + kb + col;
      __builtin_amdgcn_global_load_lds(
          (const __attribute__((address_space(1))) void*)gz,
          (__attribute__((address_space(3))) void*)&Zs[bi][j * 256], 16, 0, 0);
      __builtin_amdgcn_global_load_lds(
          (const __attribute__((address_space(1))) void*)ge,
          (__attribute__((address_space(3))) void*)&Es2[bi][j * 256], 16, 0, 0);
    }
  };

  stage(0, 0);
  for (int kt = 0; kt < 8; ++kt) {
#pragma unroll
    for (int zh = 0; zh < 2; ++zh)
#pragma unroll
      for (int eh = 0; eh < 2; ++eh)
#pragma unroll
        for (int i = 0; i < 4; ++i)
#pragma unroll
          for (int j = 0; j < 4; ++j) acc[zh][eh][i][j] = 0.f;

    for (int dc = 0; dc < 4; ++dc) {
      const int g = kt * 4 + dc;
      __syncthreads();  // implicit vmcnt(0): stage(g) landed for every wave
      if (g + 1 < 32) stage(g + 1, (g + 1) & 1);
      const float* Zb = &Zs[g & 1][0];
      const float* Eb = &Es2[g & 1][0];
#pragma unroll
      for (int d = 0; d < 16; ++d) {
        float4 za4 = *(const float4*)&Zb[d * 128 + ty4];
        float4 zb4 = *(const float4*)&Zb[d * 128 + 64 + ty4];
        float4 ea4 = *(const float4*)&Eb[d * 128 + tx4];
        float4 eb4 = *(const float4*)&Eb[d * 128 + 64 + tx4];
        const float* za = (const float*)&za4;
        const float* zb = (const float*)&zb4;
        const float* ea = (const float*)&ea4;
        const float* eb = (const float*)&eb4;
#pragma unroll
        for (int i = 0; i < 4; ++i) {
#pragma unroll
          for (int j = 0; j < 4; ++j) {
            acc[0][0][i][j] = fmaf(za[i], ea[j], acc[0][0][i][j]);
            acc[0][1][i][j] = fmaf(za[i], eb[j], acc[0][1][i][j]);
            acc[1][0][i][j] = fmaf(zb[i], ea[j], acc[1][0][i][j]);
            acc[1][1][i][j] = fmaf(zb[i], eb[j], acc[1][1][i][j]);
          }
        }
      }
    }
    // argmin update for this kt tile (k ascending for tie -> lowest index)
    const int kb = k0base + kt * 128;
    float4 e2a4 = *(const float4*)&e2[kb + tx4];
    float4 e2b4 = *(const float4*)&e2[kb + 64 + tx4];
    const float* e2a = (const float*)&e2a4;
    const float* e2b = (const float*)&e2b4;
#pragma unroll
    for (int zh = 0; zh < 2; ++zh)
#pragma unroll
      for (int i = 0; i < 4; ++i) {
#pragma unroll
        for (int j = 0; j < 4; ++j) {
          float s = fmaf(-2.f, acc[zh][0][i][j], e2a[j]);
          if (s < mv[zh][i]) { mv[zh][i] = s; mi[zh][i] = kb + tx4 + j; }
        }
#pragma unroll
        for (int j = 0; j < 4; ++j) {
          float s = fmaf(-2.f, acc[zh][1][i][j], e2b[j]);
          if (s < mv[zh][i]) { mv[zh][i] = s; mi[zh][i] = kb + 64 + tx4 + j; }
        }
      }
  }
  // reduce across the 16 tx lanes
#pragma unroll
  for (int off = 8; off >= 1; off >>= 1) {
#pragma unroll
    for (int zh = 0; zh < 2; ++zh)
#pragma unroll
      for (int i = 0; i < 4; ++i) {
        float ov = __shfl_xor(mv[zh][i], off);
        int oi = __shfl_xor(mi[zh][i], off);
        if (ov < mv[zh][i] || (ov == mv[zh][i] && oi < mi[zh][i])) {
          mv[zh][i] = ov;
          mi[zh][i] = oi;
        }
      }
  }
  if ((t & 15) == 0) {
    const int ty = (t >> 4) & 15;
#pragma unroll
    for (int zh = 0; zh < 2; ++zh)
#pragma unroll
      for (int i = 0; i < 4; ++i) {
        int row = r0 + zh * 64 + ty * 4 + i;
        pmv[kh * NROWS + row] = mv[zh][i];
        pmi[kh * NROWS + row] = mi[zh][i];
      }
  }
}

// ---------------- K4: combine 8 k-split partials; emit final index as float
__global__ __launch_bounds__(256) void k_pick(const float* __restrict__ pmv,
                                              const int* __restrict__ pmi,
                                              float* __restrict__ idxf) {
  int n = blockIdx.x * 256 + threadIdx.x;
  float bv = pmv[n];
  int bi = pmi[n];
#pragma unroll
  for (int p = 1; p < 8; ++p) {
    float v = pmv[p * NROWS + n];
    int i = pmi[p * NROWS + n];
    if (v < bv || (v == bv && i < bi)) { bv = v; bi = i; }
  }
  idxf[n] = (float)bi;
}

// ---------------- K5: decoder 1x1 conv from gathered codebook rows
// grid 1024: bh = bid>>1, oh = bid&1 (256-out-channel half)
__global__ __launch_bounds__(256) void k_dec(const float* __restrict__ emb,
                                             const float* __restrict__ w_out,
                                             const float* __restrict__ b_out,
                                             const float* __restrict__ idxf,
                                             float* __restrict__ out) {
  __shared__ float Qt[DDIM][36];  // [d][w]
  __shared__ float Wt[DDIM][68];  // [d][o-local]
  const int bid = blockIdx.x;
  const int bh = bid >> 1, oh = bid & 1;
  const int b = bh >> 5, h = bh & 31;
  const int t = threadIdx.x;
  const int w = t & 31, og = t >> 5;
  {
    const int dd = t & 63, r4 = t >> 6;
#pragma unroll
    for (int i = 0; i < 8; ++i) {
      int r = r4 + 4 * i;  // 0..31
      int qi = (int)idxf[bh * 32 + r];
      Qt[dd][r] = emb[(size_t)qi * DDIM + dd];
    }
  }
  for (int ob = 0; ob < 4; ++ob) {
    const int o0 = oh * 256 + ob * 64;
    __syncthreads();  // prev Wt consumed (and Qt visible on first pass)
#pragma unroll
    for (int i = 0; i < 16; ++i) {
      int e = t + 256 * i;
      int oo = e >> 6, dd = e & 63;
      Wt[dd][oo] = w_out[(size_t)(o0 + oo) * DDIM + dd];
    }
    __syncthreads();
    float a[8];
#pragma unroll
    for (int j = 0; j < 8; ++j) a[j] = b_out[o0 + og * 8 + j];
#pragma unroll 4
    for (int d = 0; d < 64; ++d) {
      float qv = Qt[d][w];
      const float4 w0 = *(const float4*)&Wt[d][og * 8];
      const float4 w1 = *(const float4*)&Wt[d][og * 8 + 4];
      a[0] = fmaf(qv, w0.x, a[0]);
      a[1] = fmaf(qv, w0.y, a[1]);
      a[2] = fmaf(qv, w0.z, a[2]);
      a[3] = fmaf(qv, w0.w, a[3]);
      a[4] = fmaf(qv, w1.x, a[4]);
      a[5] = fmaf(qv, w1.y, a[5]);
      a[6] = fmaf(qv, w1.z, a[6]);
      a[7] = fmaf(qv, w1.w, a[7]);
    }
    float* op = out + (((size_t)b * OUTC + o0 + og * 8) * 32 + h) * 32 + w;
#pragma unroll
    for (int j = 0; j < 8; ++j) op[(size_t)j * 1024] = a[j];
  }
}

extern "C" void kernel_launch(void* const* d_in, const int* in_sizes, int n_in,
                              void* d_out, int out_size, void* d_ws, size_t ws_size,
                              hipStream_t stream) {
  const float* x = (const float*)d_in[0];
  const float* w_in = (const float*)d_in[1];
  const float* b_in = (const float*)d_in[2];
  const float* emb = (const float*)d_in[3];
  const float* w_out = (const float*)d_in[4];
  const float* b_out = (const float*)d_in[5];
  float* out = (float*)d_out;

  float* zt = out + OFF_ZT;
  float* et = out + OFF_ET;
  float* e2 = out + OFF_E2;
  float* pmv = out + OFF_PMV;
  int* pmi = (int*)(out + OFF_PMI);
  float* idxf = out + OUT_MAIN;  // final indices output (as float), d_out tail

  k_enc<<<1024, 256, 0, stream>>>(x, w_in, b_in, zt);
  k_prep<<<128, 256, 0, stream>>>(emb, et, e2);
  k_argmin<<<1024, 256, 0, stream>>>(zt, et, e2, pmv, pmi);
  k_pick<<<64, 256, 0, stream>>>(pmv, pmi, idxf);
  k_dec<<<1024, 256, 0, stream>>>(emb, w_out, b_out, idxf, out);
}

// Round 3
// 368.549 us; speedup vs baseline: 2.7474x; 2.7474x over previous
//
#include <hip/hip_runtime.h>

#define NROWS 16384
#define DDIM 64
#define KCB 8192
#define CIN 512
#define OUTC 512
#define OUT_MAIN 8388608

typedef float f4 __attribute__((ext_vector_type(4)));

// scratch offsets within d_out (in floats)
#define OFF_ZT 0          // zt[64][16384]
#define OFF_ET 1048576    // et[64][8192]
#define OFF_E2 1572864    // e2[8192]
#define OFF_PMV 1581056   // pmv[8][16384]
#define OFF_PMI 1712128   // pmi[8][16384] (ints)

// ---------------- K1: encoder 1x1 conv, writes z TRANSPOSED zt[d][n]
__global__ __launch_bounds__(256) void k_enc(const float* __restrict__ x,
                                             const float* __restrict__ w_in,
                                             const float* __restrict__ b_in,
                                             float* __restrict__ zt) {
  __shared__ float Wt[128][36];  // [c][dd], dd in 0..31
  const int bid = blockIdx.x;
  const int bh = bid >> 1, dh = bid & 1;
  const int b = bh >> 5, h = bh & 31;
  const int d0 = dh * 32;
  const int t = threadIdx.x;
  const int w = t & 31, dg = t >> 5;  // dg 0..7 -> d = d0+dg*4..+3
  float acc[4];
#pragma unroll
  for (int j = 0; j < 4; ++j) acc[j] = b_in[d0 + dg * 4 + j];
  const float* xb = x + ((size_t)b * CIN * 1024) + h * 32 + w;
  for (int c0 = 0; c0 < CIN; c0 += 128) {
    __syncthreads();
#pragma unroll
    for (int i = 0; i < 16; ++i) {
      int e = t + 256 * i;
      int cc = e & 127, dd = e >> 7;
      Wt[cc][dd] = w_in[(size_t)(d0 + dd) * CIN + c0 + cc];
    }
    __syncthreads();
#pragma unroll 8
    for (int c = 0; c < 128; ++c) {
      float xv = xb[(size_t)(c0 + c) * 1024];
      const f4 wv = *(const f4*)&Wt[c][dg * 4];
      acc[0] = fmaf(xv, wv.x, acc[0]);
      acc[1] = fmaf(xv, wv.y, acc[1]);
      acc[2] = fmaf(xv, wv.z, acc[2]);
      acc[3] = fmaf(xv, wv.w, acc[3]);
    }
  }
  const int n = bh * 32 + w;
#pragma unroll
  for (int j = 0; j < 4; ++j) zt[(size_t)(d0 + dg * 4 + j) * NROWS + n] = acc[j];
}

// ---------------- K2: transpose emb -> et[d][k], and e2[k] = ||emb[k]||^2
__global__ __launch_bounds__(256) void k_prep(const float* __restrict__ emb,
                                              float* __restrict__ et,
                                              float* __restrict__ e2) {
  __shared__ float Es[DDIM][68];  // [d][k-local]
  const int k0 = blockIdx.x * 64;
  const int t = threadIdx.x;
  {
    const int dd = t & 63, kl4 = t >> 6;
#pragma unroll
    for (int i = 0; i < 16; ++i) {
      int kl = kl4 + 4 * i;
      Es[dd][kl] = emb[(size_t)(k0 + kl) * DDIM + dd];
    }
  }
  __syncthreads();
  if (t < 64) {
    float s = 0.f;
#pragma unroll
    for (int d = 0; d < 64; ++d) s = fmaf(Es[d][t], Es[d][t], s);
    e2[k0 + t] = s;
  }
  const int dd = t >> 2;
#pragma unroll
  for (int i = 0; i < 4; ++i) {
    int ch = (t & 3) + 4 * i;  // 0..15 float4 chunks of the 64-k row
    f4 v = *(const f4*)&Es[dd][ch * 4];
    *(f4*)&et[(size_t)dd * KCB + k0 + ch * 4] = v;
  }
}

// ---------------- K3: fused distance-GEMM + argmin
// grid 1024: rt = bid&127 (128-row tile), kh = bid>>7 (1024-k range)
// block tile 128 rows x 128 ks, d-chunked by 16, double-buffered LDS,
// thread tile 8x8 = (4+4 rows at stride 64) x (4+4 ks at stride 64)
__global__ __launch_bounds__(256, 4) void k_argmin(const float* __restrict__ zt,
                                                   const float* __restrict__ et,
                                                   const float* __restrict__ e2,
                                                   float* __restrict__ pmv,
                                                   int* __restrict__ pmi) {
  __shared__ float Zs[2][2048];   // [buf][16 d][128 r]
  __shared__ float Es2[2][2048];  // [buf][16 d][128 k]
  const int bid = blockIdx.x;
  const int rt = bid & 127, kh = bid >> 7;
  const int r0 = rt * 128;
  const int k0base = kh * 1024;
  const int t = threadIdx.x;
  const int tx4 = (t & 15) * 4;
  const int ty4 = ((t >> 4) & 15) * 4;
  const int l = t & 63, ws = t >> 6;

  // 16 f4 accumulators, all statically indexed
  f4 a00[4], a01[4], a10[4], a11[4];
  float mvA[2][4], mvB[2][4];
  int miA[2][4], miB[2][4];
#pragma unroll
  for (int zh = 0; zh < 2; ++zh)
#pragma unroll
    for (int i = 0; i < 4; ++i) {
      mvA[zh][i] = 3.4028235e38f; miA[zh][i] = 0;
      mvB[zh][i] = 3.4028235e38f; miB[zh][i] = 0;
    }

  auto stage = [&](int g, int bi) {
    const int kt = g >> 2, dc = g & 3;
    const int d0 = dc * 16;
    const int kb = k0base + kt * 128;
#pragma unroll
    for (int jj = 0; jj < 2; ++jj) {
      const int j = 2 * ws + jj;          // 0..7, wave-uniform
      const int drow = 2 * j + (l >> 5);  // 0..15
      const int col = (l & 31) * 4;
      const float* gz = zt + (size_t)(d0 + drow) * NROWS + r0 + col;
      const float* ge = et + (size_t)(d0 + drow) * KCB + kb + col;
      __builtin_amdgcn_global_load_lds(
          (const __attribute__((address_space(1))) void*)gz,
          (__attribute__((address_space(3))) void*)&Zs[bi][j * 256], 16, 0, 0);
      __builtin_amdgcn_global_load_lds(
          (const __attribute__((address_space(1))) void*)ge,
          (__attribute__((address_space(3))) void*)&Es2[bi][j * 256], 16, 0, 0);
    }
  };

  stage(0, 0);
  for (int kt = 0; kt < 8; ++kt) {
    {
      const f4 zero = {0.f, 0.f, 0.f, 0.f};
#pragma unroll
      for (int i = 0; i < 4; ++i) { a00[i] = zero; a01[i] = zero; a10[i] = zero; a11[i] = zero; }
    }
    for (int dc = 0; dc < 4; ++dc) {
      const int g = kt * 4 + dc;
      __syncthreads();  // implicit vmcnt(0): stage(g) landed for every wave
      if (g + 1 < 32) stage(g + 1, (g + 1) & 1);
      const float* Zb = &Zs[g & 1][0];
      const float* Eb = &Es2[g & 1][0];
#pragma unroll
      for (int d = 0; d < 16; ++d) {
        const f4 zA = *(const f4*)&Zb[d * 128 + ty4];
        const f4 zB = *(const f4*)&Zb[d * 128 + 64 + ty4];
        const f4 eA = *(const f4*)&Eb[d * 128 + tx4];
        const f4 eB = *(const f4*)&Eb[d * 128 + 64 + tx4];
        a00[0] += zA.x * eA; a00[1] += zA.y * eA; a00[2] += zA.z * eA; a00[3] += zA.w * eA;
        a01[0] += zA.x * eB; a01[1] += zA.y * eB; a01[2] += zA.z * eB; a01[3] += zA.w * eB;
        a10[0] += zB.x * eA; a10[1] += zB.y * eA; a10[2] += zB.z * eA; a10[3] += zB.w * eA;
        a11[0] += zB.x * eB; a11[1] += zB.y * eB; a11[2] += zB.z * eB; a11[3] += zB.w * eB;
      }
    }
    // argmin update for this kt tile
    const int kb = k0base + kt * 128;
    const f4 e2A = *(const f4*)&e2[kb + tx4];
    const f4 e2B = *(const f4*)&e2[kb + 64 + tx4];
#define UPD(mv, mi, sv, ki) if ((sv) < (mv)) { (mv) = (sv); (mi) = (ki); }
#pragma unroll
    for (int i = 0; i < 4; ++i) {
      {
        const f4 s0 = e2A - 2.0f * a00[i];
        UPD(mvA[0][i], miA[0][i], s0.x, kb + tx4);
        UPD(mvA[0][i], miA[0][i], s0.y, kb + tx4 + 1);
        UPD(mvA[0][i], miA[0][i], s0.z, kb + tx4 + 2);
        UPD(mvA[0][i], miA[0][i], s0.w, kb + tx4 + 3);
        const f4 s1 = e2B - 2.0f * a01[i];
        UPD(mvB[0][i], miB[0][i], s1.x, kb + 64 + tx4);
        UPD(mvB[0][i], miB[0][i], s1.y, kb + 64 + tx4 + 1);
        UPD(mvB[0][i], miB[0][i], s1.z, kb + 64 + tx4 + 2);
        UPD(mvB[0][i], miB[0][i], s1.w, kb + 64 + tx4 + 3);
      }
      {
        const f4 s0 = e2A - 2.0f * a10[i];
        UPD(mvA[1][i], miA[1][i], s0.x, kb + tx4);
        UPD(mvA[1][i], miA[1][i], s0.y, kb + tx4 + 1);
        UPD(mvA[1][i], miA[1][i], s0.z, kb + tx4 + 2);
        UPD(mvA[1][i], miA[1][i], s0.w, kb + tx4 + 3);
        const f4 s1 = e2B - 2.0f * a11[i];
        UPD(mvB[1][i], miB[1][i], s1.x, kb + 64 + tx4);
        UPD(mvB[1][i], miB[1][i], s1.y, kb + 64 + tx4 + 1);
        UPD(mvB[1][i], miB[1][i], s1.z, kb + 64 + tx4 + 2);
        UPD(mvB[1][i], miB[1][i], s1.w, kb + 64 + tx4 + 3);
      }
    }
#undef UPD
  }
  // merge the two k-column groups (A at tx4, B at 64+tx4); tie -> lower index
#pragma unroll
  for (int zh = 0; zh < 2; ++zh)
#pragma unroll
    for (int i = 0; i < 4; ++i) {
      if (mvB[zh][i] < mvA[zh][i] ||
          (mvB[zh][i] == mvA[zh][i] && miB[zh][i] < miA[zh][i])) {
        mvA[zh][i] = mvB[zh][i];
        miA[zh][i] = miB[zh][i];
      }
    }
  // reduce across the 16 tx lanes
#pragma unroll
  for (int off = 8; off >= 1; off >>= 1) {
#pragma unroll
    for (int zh = 0; zh < 2; ++zh)
#pragma unroll
      for (int i = 0; i < 4; ++i) {
        float ov = __shfl_xor(mvA[zh][i], off);
        int oi = __shfl_xor(miA[zh][i], off);
        if (ov < mvA[zh][i] || (ov == mvA[zh][i] && oi < miA[zh][i])) {
          mvA[zh][i] = ov;
          miA[zh][i] = oi;
        }
      }
  }
  if ((t & 15) == 0) {
    const int ty = (t >> 4) & 15;
#pragma unroll
    for (int zh = 0; zh < 2; ++zh)
#pragma unroll
      for (int i = 0; i < 4; ++i) {
        int row = r0 + zh * 64 + ty * 4 + i;
        pmv[kh * NROWS + row] = mvA[zh][i];
        pmi[kh * NROWS + row] = miA[zh][i];
      }
  }
}

// ---------------- K4: combine 8 k-split partials; emit final index as float
__global__ __launch_bounds__(256) void k_pick(const float* __restrict__ pmv,
                                              const int* __restrict__ pmi,
                                              float* __restrict__ idxf) {
  int n = blockIdx.x * 256 + threadIdx.x;
  float bv = pmv[n];
  int bi = pmi[n];
#pragma unroll
  for (int p = 1; p < 8; ++p) {
    float v = pmv[p * NROWS + n];
    int i = pmi[p * NROWS + n];
    if (v < bv || (v == bv && i < bi)) { bv = v; bi = i; }
  }
  idxf[n] = (float)bi;
}

// ---------------- K5: decoder 1x1 conv from gathered codebook rows
__global__ __launch_bounds__(256) void k_dec(const float* __restrict__ emb,
                                             const float* __restrict__ w_out,
                                             const float* __restrict__ b_out,
                                             const float* __restrict__ idxf,
                                             float* __restrict__ out) {
  __shared__ float Qt[DDIM][36];  // [d][w]
  __shared__ float Wt[DDIM][68];  // [d][o-local]
  const int bid = blockIdx.x;
  const int bh = bid >> 1, oh = bid & 1;
  const int b = bh >> 5, h = bh & 31;
  const int t = threadIdx.x;
  const int w = t & 31, og = t >> 5;
  {
    const int dd = t & 63, r4 = t >> 6;
#pragma unroll
    for (int i = 0; i < 8; ++i) {
      int r = r4 + 4 * i;  // 0..31
      int qi = (int)idxf[bh * 32 + r];
      Qt[dd][r] = emb[(size_t)qi * DDIM + dd];
    }
  }
  for (int ob = 0; ob < 4; ++ob) {
    const int o0 = oh * 256 + ob * 64;
    __syncthreads();  // prev Wt consumed (and Qt visible on first pass)
#pragma unroll
    for (int i = 0; i < 16; ++i) {
      int e = t + 256 * i;
      int oo = e >> 6, dd = e & 63;
      Wt[dd][oo] = w_out[(size_t)(o0 + oo) * DDIM + dd];
    }
    __syncthreads();
    float a[8];
#pragma unroll
    for (int j = 0; j < 8; ++j) a[j] = b_out[o0 + og * 8 + j];
#pragma unroll 4
    for (int d = 0; d < 64; ++d) {
      float qv = Qt[d][w];
      const f4 w0 = *(const f4*)&Wt[d][og * 8];
      const f4 w1 = *(const f4*)&Wt[d][og * 8 + 4];
      a[0] = fmaf(qv, w0.x, a[0]);
      a[1] = fmaf(qv, w0.y, a[1]);
      a[2] = fmaf(qv, w0.z, a[2]);
      a[3] = fmaf(qv, w0.w, a[3]);
      a[4] = fmaf(qv, w1.x, a[4]);
      a[5] = fmaf(qv, w1.y, a[5]);
      a[6] = fmaf(qv, w1.z, a[6]);
      a[7] = fmaf(qv, w1.w, a[7]);
    }
    float* op = out + (((size_t)b * OUTC + o0 + og * 8) * 32 + h) * 32 + w;
#pragma unroll
    for (int j = 0; j < 8; ++j) op[(size_t)j * 1024] = a[j];
  }
}

extern "C" void kernel_launch(void* const* d_in, const int* in_sizes, int n_in,
                              void* d_out, int out_size, void* d_ws, size_t ws_size,
                              hipStream_t stream) {
  const float* x = (const float*)d_in[0];
  const float* w_in = (const float*)d_in[1];
  const float* b_in = (const float*)d_in[2];
  const float* emb = (const float*)d_in[3];
  const float* w_out = (const float*)d_in[4];
  const float* b_out = (const float*)d_in[5];
  float* out = (float*)d_out;

  float* zt = out + OFF_ZT;
  float* et = out + OFF_ET;
  float* e2 = out + OFF_E2;
  float* pmv = out + OFF_PMV;
  int* pmi = (int*)(out + OFF_PMI);
  float* idxf = out + OUT_MAIN;  // final indices output (as float), d_out tail

  k_enc<<<1024, 256, 0, stream>>>(x, w_in, b_in, zt);
  k_prep<<<128, 256, 0, stream>>>(emb, et, e2);
  k_argmin<<<1024, 256, 0, stream>>>(zt, et, e2, pmv, pmi);
  k_pick<<<64, 256, 0, stream>>>(pmv, pmi, idxf);
  k_dec<<<1024, 256, 0, stream>>>(emb, w_out, b_out, idxf, out);
}

// Round 5
// 252.658 us; speedup vs baseline: 4.0076x; 1.4587x over previous
//
#include <hip/hip_runtime.h>

#define NROWS 16384
#define DDIM 64
#define KCB 8192
#define CIN 512
#define OUTC 512
#define OUT_MAIN 8388608

typedef float f4 __attribute__((ext_vector_type(4)));
typedef float f32x16 __attribute__((ext_vector_type(16)));
typedef __bf16 bf16x4 __attribute__((ext_vector_type(4)));
typedef __bf16 bf16x8 __attribute__((ext_vector_type(8)));

// d_out scratch layout (f32 units). k_dec overwrites [0, OUT_MAIN) last.
#define OFF_ZBF 0         // zbf: 3*4*512*64*8 = 3,145,728 bf16 = 1,572,864 f32
#define OFF_EBF 1572864   // ebf: 3*4*256*64*8 = 1,572,864 bf16 = 786,432 f32
#define OFF_E2H 2359296   // e2h[8192] = 0.5*||e||^2
#define OFF_PMV 2367488   // pmv[16][16384] (score partial max)
#define OFF_PMI 2629632   // pmi[16][16384] (int)
#define ZS_STRIDE 1048576  // bf16 elems per z split level (4*512*64*8)
#define ES_STRIDE 524288   // bf16 elems per e split level (4*256*64*8)

// ---------------- K1: encoder 1x1 conv -> bf16 3-split in MFMA-frag layout
// zbf[s][kb][g][lane][j]: lane = khalf*32 + (row&31), j = k&7,
// value = split_s( z[g*32 + (row&31)][kb*16 + khalf*8 + j] )
__global__ __launch_bounds__(256) void k_enc(const float* __restrict__ x,
                                             const float* __restrict__ w_in,
                                             const float* __restrict__ b_in,
                                             __bf16* __restrict__ zbf) {
  __shared__ float Wt[128][36];  // [c][dd], dd in 0..31
  const int bid = blockIdx.x;
  const int g = bid >> 1, dh = bid & 1;  // g = rowgroup (b*32+h), dh = d-half
  const int b = g >> 5, h = g & 31;
  const int d0 = dh * 32;
  const int t = threadIdx.x;
  const int w = t & 31, dg = t >> 5;  // w = row-in-group, dg -> d = d0+dg*4..+3
  float acc[4];
#pragma unroll
  for (int j = 0; j < 4; ++j) acc[j] = b_in[d0 + dg * 4 + j];
  const float* xb = x + ((size_t)b * CIN * 1024) + h * 32 + w;
  for (int c0 = 0; c0 < CIN; c0 += 128) {
    __syncthreads();
#pragma unroll
    for (int i = 0; i < 16; ++i) {
      int e = t + 256 * i;
      int cc = e & 127, dd = e >> 7;
      Wt[cc][dd] = w_in[(size_t)(d0 + dd) * CIN + c0 + cc];
    }
    __syncthreads();
#pragma unroll 8
    for (int c = 0; c < 128; ++c) {
      float xv = xb[(size_t)(c0 + c) * 1024];
      const f4 wv = *(const f4*)&Wt[c][dg * 4];
      acc[0] = fmaf(xv, wv.x, acc[0]);
      acc[1] = fmaf(xv, wv.y, acc[1]);
      acc[2] = fmaf(xv, wv.z, acc[2]);
      acc[3] = fmaf(xv, wv.w, acc[3]);
    }
  }
  // split epilogue
  const int K0 = dh * 32 + dg * 4;
  const int kb = K0 >> 4, khalf = (K0 >> 3) & 1, j0 = K0 & 7;
  bf16x4 s0, s1, s2;
#pragma unroll
  for (int j = 0; j < 4; ++j) {
    float v = acc[j];
    __bf16 a0 = (__bf16)v;
    float r1 = v - (float)a0;
    __bf16 a1 = (__bf16)r1;
    float r2 = r1 - (float)a1;
    __bf16 a2 = (__bf16)r2;
    s0[j] = a0; s1[j] = a1; s2[j] = a2;
  }
  const size_t base = ((size_t)(kb * 512 + g) * 64 + khalf * 32 + w) * 8 + j0;
  *(bf16x4*)(zbf + base) = s0;
  *(bf16x4*)(zbf + base + ZS_STRIDE) = s1;
  *(bf16x4*)(zbf + base + 2 * ZS_STRIDE) = s2;
}

// ---------------- K2: emb -> bf16 3-split frag layout + e2h = 0.5*||e||^2
// ebf[s][kb][cg][lane][j]: lane = khalf*32 + (code&31), value = split_s(emb[code][k])
__global__ __launch_bounds__(256) void k_prep(const float* __restrict__ emb,
                                              __bf16* __restrict__ ebf,
                                              float* __restrict__ e2h) {
  __shared__ float s2[4][64];
  const int C0 = blockIdx.x * 64;
  const int t = threadIdx.x;
  const int cl = t & 63, kb = t >> 6;
  const int c = C0 + cl;
  const int cg = blockIdx.x * 2 + (cl >> 5);
  float e[16];
  {
    const f4* ep = (const f4*)(emb + (size_t)c * DDIM + kb * 16);
#pragma unroll
    for (int q = 0; q < 4; ++q) {
      f4 v = ep[q];
      e[q * 4 + 0] = v.x; e[q * 4 + 1] = v.y; e[q * 4 + 2] = v.z; e[q * 4 + 3] = v.w;
    }
  }
  float sq = 0.f;
#pragma unroll
  for (int i = 0; i < 16; ++i) sq = fmaf(e[i], e[i], sq);
  s2[kb][cl] = sq;
  bf16x8 v0[2], v1[2], v2[2];
#pragma unroll
  for (int i = 0; i < 16; ++i) {
    float v = e[i];
    __bf16 a0 = (__bf16)v;
    float r1 = v - (float)a0;
    __bf16 a1 = (__bf16)r1;
    float r2 = r1 - (float)a1;
    __bf16 a2 = (__bf16)r2;
    v0[i >> 3][i & 7] = a0; v1[i >> 3][i & 7] = a1; v2[i >> 3][i & 7] = a2;
  }
#pragma unroll
  for (int khalf = 0; khalf < 2; ++khalf) {
    const size_t dst = ((size_t)(kb * 256 + cg) * 64 + khalf * 32 + (cl & 31)) * 8;
    *(bf16x8*)(ebf + dst) = v0[khalf];
    *(bf16x8*)(ebf + dst + ES_STRIDE) = v1[khalf];
    *(bf16x8*)(ebf + dst + 2 * ES_STRIDE) = v2[khalf];
  }
  __syncthreads();
  if (t < 64)
    e2h[C0 + t] = 0.5f * (s2[0][t] + s2[1][t] + s2[2][t] + s2[3][t]);
}

// ---------------- K3: split-MFMA distance GEMM + per-lane argmax fold
// 1 wave per block. A = emb (codes = M), B = z (rows = N).
// C layout: n(row) = lane&31; m(code-offset) = (reg&3)+8*(reg>>2)+4*(lane>>5).
// acc is initialized to -e2h[code]; MFMA adds dot -> score = dot - ||e||^2/2.
// Within a lane candidates are visited in ascending code order, so strict '>'
// keeps the lowest index on ties.
__global__ __launch_bounds__(64, 2) void k_argmin(const __bf16* __restrict__ zbf,
                                                  const __bf16* __restrict__ ebf,
                                                  const float* __restrict__ e2h,
                                                  float* __restrict__ pmv,
                                                  int* __restrict__ pmi) {
  const int wid = blockIdx.x;
  const int rt = wid >> 4, chunk = wid & 15;
  const int R = rt * 64;
  const int l = threadIdx.x;
  const int h4 = (l >> 5) * 4;

  // persistent z fragments: [split][kb][rn]
  bf16x8 zf0[4][2], zf1[4][2], zf2[4][2];
#pragma unroll
  for (int kb = 0; kb < 4; ++kb)
#pragma unroll
    for (int rn = 0; rn < 2; ++rn) {
      const int g = (R >> 5) + rn;
      zf0[kb][rn] = *(const bf16x8*)(zbf + ((size_t)(kb * 512 + g) * 64 + l) * 8);
      zf1[kb][rn] = *(const bf16x8*)(zbf + ZS_STRIDE + ((size_t)(kb * 512 + g) * 64 + l) * 8);
      zf2[kb][rn] = *(const bf16x8*)(zbf + 2 * ZS_STRIDE + ((size_t)(kb * 512 + g) * 64 + l) * 8);
    }
  float mv0 = -3.4028235e38f, mv1 = -3.4028235e38f;
  int mi0 = 0, mi1 = 0;

#pragma unroll 1
  for (int st = 0; st < 8; ++st) {
    const int cbase = chunk * 512 + st * 64;
    const int cg0 = cbase >> 5;
    const float* e2p = e2h + cbase;
    f32x16 acc[2][2];
#pragma unroll
    for (int cm = 0; cm < 2; ++cm) {
#pragma unroll
      for (int q = 0; q < 4; ++q) {
        const f4 e2q = *(const f4*)(e2p + cm * 32 + h4 + q * 8);
#pragma unroll
        for (int i = 0; i < 4; ++i) {
          acc[cm][0][q * 4 + i] = -e2q[i];
          acc[cm][1][q * 4 + i] = -e2q[i];
        }
      }
    }

    bf16x8 af[4][2];
#define LOAD_AF(b)                                                                 \
  {                                                                                \
    _Pragma("unroll") for (int kb = 0; kb < 4; ++kb)                               \
        _Pragma("unroll") for (int cm = 0; cm < 2; ++cm) af[kb][cm] =              \
        *(const bf16x8*)(ebf + (size_t)(b)*ES_STRIDE +                             \
                         ((size_t)(kb * 256 + cg0 + cm) * 64 + l) * 8);            \
  }
#define SWEEP(ZF)                                                                  \
  {                                                                                \
    _Pragma("unroll") for (int kb = 0; kb < 4; ++kb)                               \
        _Pragma("unroll") for (int cm = 0; cm < 2; ++cm)                           \
        _Pragma("unroll") for (int rn = 0; rn < 2; ++rn) acc[cm][rn] =             \
        __builtin_amdgcn_mfma_f32_32x32x16_bf16(af[kb][cm], ZF[kb][rn],            \
                                                acc[cm][rn], 0, 0, 0);             \
  }
    LOAD_AF(0);
    SWEEP(zf0); SWEEP(zf1); SWEEP(zf2);
    LOAD_AF(1);
    SWEEP(zf0); SWEEP(zf1);
    LOAD_AF(2);
    SWEEP(zf0);
#undef LOAD_AF
#undef SWEEP
    // fold: argmax of score; strict '>' + ascending visit order = lowest-tie
#pragma unroll
    for (int cm = 0; cm < 2; ++cm) {
#pragma unroll
      for (int q = 0; q < 4; ++q) {
#pragma unroll
        for (int i = 0; i < 4; ++i) {
          const int reg = q * 4 + i;
          const int code = cbase + cm * 32 + h4 + q * 8 + i;
          const float s0 = acc[cm][0][reg];
          if (s0 > mv0) { mv0 = s0; mi0 = code; }
          const float s1 = acc[cm][1][reg];
          if (s1 > mv1) { mv1 = s1; mi1 = code; }
        }
      }
    }
  }
  // merge lane l with l^32 (same row, interleaved code sets -> full tie-break)
  {
    float ov = __shfl_xor(mv0, 32); int oi = __shfl_xor(mi0, 32);
    if (ov > mv0 || (ov == mv0 && oi < mi0)) { mv0 = ov; mi0 = oi; }
    ov = __shfl_xor(mv1, 32); oi = __shfl_xor(mi1, 32);
    if (ov > mv1 || (ov == mv1 && oi < mi1)) { mv1 = ov; mi1 = oi; }
  }
  if (l < 32) {
    const int row0 = R + l, row1 = R + 32 + l;
    pmv[chunk * NROWS + row0] = mv0;
    pmi[chunk * NROWS + row0] = mi0;
    pmv[chunk * NROWS + row1] = mv1;
    pmi[chunk * NROWS + row1] = mi1;
  }
}

// ---------------- K4: combine 16 chunk partials (max score; chunks ascend so
// strict '>' keeps the lowest index on ties)
__global__ __launch_bounds__(256) void k_pick(const float* __restrict__ pmv,
                                              const int* __restrict__ pmi,
                                              float* __restrict__ idxf) {
  int n = blockIdx.x * 256 + threadIdx.x;
  float bv = pmv[n];
  int bi = pmi[n];
#pragma unroll
  for (int p = 1; p < 16; ++p) {
    float v = pmv[p * NROWS + n];
    int i = pmi[p * NROWS + n];
    if (v > bv) { bv = v; bi = i; }
  }
  idxf[n] = (float)bi;
}

// ---------------- K5: decoder 1x1 conv from gathered codebook rows
__global__ __launch_bounds__(256) void k_dec(const float* __restrict__ emb,
                                             const float* __restrict__ w_out,
                                             const float* __restrict__ b_out,
                                             const float* __restrict__ idxf,
                                             float* __restrict__ out) {
  __shared__ float Qt[DDIM][36];  // [d][w]
  __shared__ float Wt[DDIM][68];  // [d][o-local]
  const int bid = blockIdx.x;
  const int bh = bid >> 1, oh = bid & 1;
  const int b = bh >> 5, h = bh & 31;
  const int t = threadIdx.x;
  const int w = t & 31, og = t >> 5;
  {
    const int dd = t & 63, r4 = t >> 6;
#pragma unroll
    for (int i = 0; i < 8; ++i) {
      int r = r4 + 4 * i;  // 0..31
      int qi = (int)idxf[bh * 32 + r];
      Qt[dd][r] = emb[(size_t)qi * DDIM + dd];
    }
  }
  for (int ob = 0; ob < 4; ++ob) {
    const int o0 = oh * 256 + ob * 64;
    __syncthreads();
#pragma unroll
    for (int i = 0; i < 16; ++i) {
      int e = t + 256 * i;
      int oo = e >> 6, dd = e & 63;
      Wt[dd][oo] = w_out[(size_t)(o0 + oo) * DDIM + dd];
    }
    __syncthreads();
    float a[8];
#pragma unroll
    for (int j = 0; j < 8; ++j) a[j] = b_out[o0 + og * 8 + j];
#pragma unroll 4
    for (int d = 0; d < 64; ++d) {
      float qv = Qt[d][w];
      const f4 w0 = *(const f4*)&Wt[d][og * 8];
      const f4 w1 = *(const f4*)&Wt[d][og * 8 + 4];
      a[0] = fmaf(qv, w0.x, a[0]);
      a[1] = fmaf(qv, w0.y, a[1]);
      a[2] = fmaf(qv, w0.z, a[2]);
      a[3] = fmaf(qv, w0.w, a[3]);
      a[4] = fmaf(qv, w1.x, a[4]);
      a[5] = fmaf(qv, w1.y, a[5]);
      a[6] = fmaf(qv, w1.z, a[6]);
      a[7] = fmaf(qv, w1.w, a[7]);
    }
    float* op = out + (((size_t)b * OUTC + o0 + og * 8) * 32 + h) * 32 + w;
#pragma unroll
    for (int j = 0; j < 8; ++j) op[(size_t)j * 1024] = a[j];
  }
}

extern "C" void kernel_launch(void* const* d_in, const int* in_sizes, int n_in,
                              void* d_out, int out_size, void* d_ws, size_t ws_size,
                              hipStream_t stream) {
  const float* x = (const float*)d_in[0];
  const float* w_in = (const float*)d_in[1];
  const float* b_in = (const float*)d_in[2];
  const float* emb = (const float*)d_in[3];
  const float* w_out = (const float*)d_in[4];
  const float* b_out = (const float*)d_in[5];
  float* out = (float*)d_out;

  __bf16* zbf = (__bf16*)(out + OFF_ZBF);
  __bf16* ebf = (__bf16*)(out + OFF_EBF);
  float* e2h = out + OFF_E2H;
  float* pmv = out + OFF_PMV;
  int* pmi = (int*)(out + OFF_PMI);
  float* idxf = out + OUT_MAIN;  // final indices output (as float), d_out tail

  k_enc<<<1024, 256, 0, stream>>>(x, w_in, b_in, zbf);
  k_prep<<<128, 256, 0, stream>>>(emb, ebf, e2h);
  k_argmin<<<4096, 64, 0, stream>>>(zbf, ebf, e2h, pmv, pmi);
  k_pick<<<64, 256, 0, stream>>>(pmv, pmi, idxf);
  k_dec<<<1024, 256, 0, stream>>>(emb, w_out, b_out, idxf, out);
}

// Round 6
// 242.554 us; speedup vs baseline: 4.1746x; 1.0417x over previous
//
#include <hip/hip_runtime.h>

#define NROWS 16384
#define DDIM 64
#define KCB 8192
#define CIN 512
#define OUTC 512
#define OUT_MAIN 8388608

typedef float f4 __attribute__((ext_vector_type(4)));
typedef float f32x16 __attribute__((ext_vector_type(16)));
typedef __bf16 bf16x4 __attribute__((ext_vector_type(4)));
typedef __bf16 bf16x8 __attribute__((ext_vector_type(8)));

// d_out scratch layout (f32 units). k_dec overwrites [0, OUT_MAIN) last.
#define OFF_ZBF 0         // zbf: 3*4*512*64*8 = 3,145,728 bf16 = 1,572,864 f32
#define OFF_EBF 1572864   // ebf: 3*4*256*64*8 = 1,572,864 bf16 = 786,432 f32
#define OFF_E2H 2359296   // e2h[8192] = 0.5*||e||^2
#define OFF_PMV 2367488   // pmv[16][16384] (score partial max)
#define OFF_PMI 2629632   // pmi[16][16384] (int)
#define ZS_STRIDE 1048576  // bf16 elems per z split level (4*512*64*8)
#define ES_STRIDE 524288   // bf16 elems per e split level (4*256*64*8)

// ---------------- K1: encoder 1x1 conv -> bf16 3-split in MFMA-frag layout
// zbf[s][kb][g][lane][j]: lane = khalf*32 + (row&31), j = k&7,
// value = split_s( z[g*32 + (row&31)][kb*16 + khalf*8 + j] )
__global__ __launch_bounds__(256) void k_enc(const float* __restrict__ x,
                                             const float* __restrict__ w_in,
                                             const float* __restrict__ b_in,
                                             __bf16* __restrict__ zbf) {
  __shared__ float Wt[128][36];  // [c][dd], dd in 0..31
  const int bid = blockIdx.x;
  const int g = bid >> 1, dh = bid & 1;  // g = rowgroup (b*32+h), dh = d-half
  const int b = g >> 5, h = g & 31;
  const int d0 = dh * 32;
  const int t = threadIdx.x;
  const int w = t & 31, dg = t >> 5;  // w = row-in-group, dg -> d = d0+dg*4..+3
  float acc[4];
#pragma unroll
  for (int j = 0; j < 4; ++j) acc[j] = b_in[d0 + dg * 4 + j];
  const float* xb = x + ((size_t)b * CIN * 1024) + h * 32 + w;
  for (int c0 = 0; c0 < CIN; c0 += 128) {
    __syncthreads();
#pragma unroll
    for (int i = 0; i < 16; ++i) {
      int e = t + 256 * i;
      int cc = e & 127, dd = e >> 7;
      Wt[cc][dd] = w_in[(size_t)(d0 + dd) * CIN + c0 + cc];
    }
    __syncthreads();
#pragma unroll 8
    for (int c = 0; c < 128; ++c) {
      float xv = xb[(size_t)(c0 + c) * 1024];
      const f4 wv = *(const f4*)&Wt[c][dg * 4];
      acc[0] = fmaf(xv, wv.x, acc[0]);
      acc[1] = fmaf(xv, wv.y, acc[1]);
      acc[2] = fmaf(xv, wv.z, acc[2]);
      acc[3] = fmaf(xv, wv.w, acc[3]);
    }
  }
  // split epilogue
  const int K0 = dh * 32 + dg * 4;
  const int kb = K0 >> 4, khalf = (K0 >> 3) & 1, j0 = K0 & 7;
  bf16x4 s0, s1, s2;
#pragma unroll
  for (int j = 0; j < 4; ++j) {
    float v = acc[j];
    __bf16 a0 = (__bf16)v;
    float r1 = v - (float)a0;
    __bf16 a1 = (__bf16)r1;
    float r2 = r1 - (float)a1;
    __bf16 a2 = (__bf16)r2;
    s0[j] = a0; s1[j] = a1; s2[j] = a2;
  }
  const size_t base = ((size_t)(kb * 512 + g) * 64 + khalf * 32 + w) * 8 + j0;
  *(bf16x4*)(zbf + base) = s0;
  *(bf16x4*)(zbf + base + ZS_STRIDE) = s1;
  *(bf16x4*)(zbf + base + 2 * ZS_STRIDE) = s2;
}

// ---------------- K2: emb -> bf16 3-split frag layout + e2h = 0.5*||e||^2
// ebf[s][kb][cg][lane][j]: lane = khalf*32 + (code&31), value = split_s(emb[code][k])
__global__ __launch_bounds__(256) void k_prep(const float* __restrict__ emb,
                                              __bf16* __restrict__ ebf,
                                              float* __restrict__ e2h) {
  __shared__ float s2[4][64];
  const int C0 = blockIdx.x * 64;
  const int t = threadIdx.x;
  const int cl = t & 63, kb = t >> 6;
  const int c = C0 + cl;
  const int cg = blockIdx.x * 2 + (cl >> 5);
  float e[16];
  {
    const f4* ep = (const f4*)(emb + (size_t)c * DDIM + kb * 16);
#pragma unroll
    for (int q = 0; q < 4; ++q) {
      f4 v = ep[q];
      e[q * 4 + 0] = v.x; e[q * 4 + 1] = v.y; e[q * 4 + 2] = v.z; e[q * 4 + 3] = v.w;
    }
  }
  float sq = 0.f;
#pragma unroll
  for (int i = 0; i < 16; ++i) sq = fmaf(e[i], e[i], sq);
  s2[kb][cl] = sq;
  bf16x8 v0[2], v1[2], v2[2];
#pragma unroll
  for (int i = 0; i < 16; ++i) {
    float v = e[i];
    __bf16 a0 = (__bf16)v;
    float r1 = v - (float)a0;
    __bf16 a1 = (__bf16)r1;
    float r2 = r1 - (float)a1;
    __bf16 a2 = (__bf16)r2;
    v0[i >> 3][i & 7] = a0; v1[i >> 3][i & 7] = a1; v2[i >> 3][i & 7] = a2;
  }
#pragma unroll
  for (int khalf = 0; khalf < 2; ++khalf) {
    const size_t dst = ((size_t)(kb * 256 + cg) * 64 + khalf * 32 + (cl & 31)) * 8;
    *(bf16x8*)(ebf + dst) = v0[khalf];
    *(bf16x8*)(ebf + dst + ES_STRIDE) = v1[khalf];
    *(bf16x8*)(ebf + dst + 2 * ES_STRIDE) = v2[khalf];
  }
  __syncthreads();
  if (t < 64)
    e2h[C0 + t] = 0.5f * (s2[0][t] + s2[1][t] + s2[2][t] + s2[3][t]);
}

// ---------------- K3: split-MFMA distance GEMM + per-lane argmax fold
// 4-wave blocks. Block = 128 rows x 512 codes; wave wv owns rows
// rowblk*128 + wv*32 (one z row-group, zf in registers, 48 VGPR) and sweeps
// 16 sts of 32 codes. Per st the e-fragments (3 splits x 4 kb, 12 KB) are
// staged once into LDS via global_load_lds (double-buffered, 1-barrier
// pipeline) and shared by all 4 waves.
// A = emb (codes = M), B = z (rows = N).
// C layout: n(row) = lane&31; m(code-offset) = (reg&3)+8*(reg>>2)+4*(lane>>5).
// Within a lane candidates ascend in code, so strict '>' keeps lowest index.
__global__ __launch_bounds__(256, 3) void k_argmin(const __bf16* __restrict__ zbf,
                                                   const __bf16* __restrict__ ebf,
                                                   const float* __restrict__ e2h,
                                                   float* __restrict__ pmv,
                                                   int* __restrict__ pmi) {
  __shared__ __bf16 Als[2][6144];  // [buf][12 frags x 64 lanes x 8]
  const int bid = blockIdx.x;
  const int rowblk = bid >> 4, chunk = bid & 15;
  const int t = threadIdx.x;
  const int l = t & 63;
  const int wv = t >> 6;
  const int h4 = (l >> 5) * 4;
  const int g = rowblk * 4 + wv;  // 32-row group owned by this wave

  // persistent z fragments zf[split][kb] (12 x bf16x8 = 48 VGPR)
  bf16x8 zf[3][4];
#pragma unroll
  for (int s = 0; s < 3; ++s)
#pragma unroll
    for (int kb = 0; kb < 4; ++kb)
      zf[s][kb] = *(const bf16x8*)(zbf + (size_t)s * ZS_STRIDE +
                                   ((size_t)(kb * 512 + g) * 64 + l) * 8);

  float mv = -3.4028235e38f;
  int mi = 0;

  auto stage = [&](int st, int bi) {
    const int cg = chunk * 16 + st;
#pragma unroll
    for (int i = 0; i < 3; ++i) {
      const int fi = wv * 3 + i;  // wave-uniform frag id 0..11
      const int s = fi >> 2, kb = fi & 3;
      const __bf16* src = ebf + (size_t)s * ES_STRIDE +
                          ((size_t)(kb * 256 + cg) * 64 + l) * 8;
      __builtin_amdgcn_global_load_lds(
          (const __attribute__((address_space(1))) void*)src,
          (__attribute__((address_space(3))) void*)&Als[bi][fi * 512 + l * 8],
          16, 0, 0);
    }
  };

  stage(0, 0);
#pragma unroll 1
  for (int st = 0; st < 16; ++st) {
    __syncthreads();  // drains stage(st); all waves done reading buf[st&1 ^ 1]
    if (st + 1 < 16) stage(st + 1, (st + 1) & 1);
    const __bf16* B = &Als[st & 1][0];
    const int cbase = (chunk * 16 + st) * 32;
    f32x16 acc = (f32x16)(0.0f);
    bf16x8 af[4];
#define LDAF(b)                                                              \
  {                                                                          \
    _Pragma("unroll") for (int kb = 0; kb < 4; ++kb) af[kb] =                \
        *(const bf16x8*)(B + ((b)*4 + kb) * 512 + l * 8);                    \
  }
#define SW(a)                                                                \
  {                                                                          \
    _Pragma("unroll") for (int kb = 0; kb < 4; ++kb) acc =                   \
        __builtin_amdgcn_mfma_f32_32x32x16_bf16(af[kb], zf[a][kb], acc, 0,   \
                                                0, 0);                       \
  }
    LDAF(0); SW(0); SW(1); SW(2);
    LDAF(1); SW(0); SW(1);
    LDAF(2); SW(0);
#undef LDAF
#undef SW
    // fold: score = dot - e2/2; strict '>' + ascending order = lowest-tie
    const float* e2p = e2h + cbase + h4;
#pragma unroll
    for (int q = 0; q < 4; ++q) {
      const f4 e2q = *(const f4*)(e2p + q * 8);
#pragma unroll
      for (int i = 0; i < 4; ++i) {
        const float s = acc[q * 4 + i] - e2q[i];
        if (s > mv) { mv = s; mi = cbase + h4 + q * 8 + i; }
      }
    }
  }
  // merge lane l with l^32 (same row, interleaved code sets -> full tie-break)
  {
    float ov = __shfl_xor(mv, 32);
    int oi = __shfl_xor(mi, 32);
    if (ov > mv || (ov == mv && oi < mi)) { mv = ov; mi = oi; }
  }
  if (l < 32) {
    const int row = rowblk * 128 + wv * 32 + l;
    pmv[chunk * NROWS + row] = mv;
    pmi[chunk * NROWS + row] = mi;
  }
}

// ---------------- K4: combine 16 chunk partials (max score; chunks ascend so
// strict '>' keeps the lowest index on ties)
__global__ __launch_bounds__(256) void k_pick(const float* __restrict__ pmv,
                                              const int* __restrict__ pmi,
                                              float* __restrict__ idxf) {
  int n = blockIdx.x * 256 + threadIdx.x;
  float bv = pmv[n];
  int bi = pmi[n];
#pragma unroll
  for (int p = 1; p < 16; ++p) {
    float v = pmv[p * NROWS + n];
    int i = pmi[p * NROWS + n];
    if (v > bv) { bv = v; bi = i; }
  }
  idxf[n] = (float)bi;
}

// ---------------- K5: decoder 1x1 conv from gathered codebook rows
__global__ __launch_bounds__(256) void k_dec(const float* __restrict__ emb,
                                             const float* __restrict__ w_out,
                                             const float* __restrict__ b_out,
                                             const float* __restrict__ idxf,
                                             float* __restrict__ out) {
  __shared__ float Qt[DDIM][36];  // [d][w]
  __shared__ float Wt[DDIM][68];  // [d][o-local]
  const int bid = blockIdx.x;
  const int bh = bid >> 1, oh = bid & 1;
  const int b = bh >> 5, h = bh & 31;
  const int t = threadIdx.x;
  const int w = t & 31, og = t >> 5;
  {
    const int dd = t & 63, r4 = t >> 6;
#pragma unroll
    for (int i = 0; i < 8; ++i) {
      int r = r4 + 4 * i;  // 0..31
      int qi = (int)idxf[bh * 32 + r];
      Qt[dd][r] = emb[(size_t)qi * DDIM + dd];
    }
  }
  for (int ob = 0; ob < 4; ++ob) {
    const int o0 = oh * 256 + ob * 64;
    __syncthreads();
#pragma unroll
    for (int i = 0; i < 16; ++i) {
      int e = t + 256 * i;
      int oo = e >> 6, dd = e & 63;
      Wt[dd][oo] = w_out[(size_t)(o0 + oo) * DDIM + dd];
    }
    __syncthreads();
    float a[8];
#pragma unroll
    for (int j = 0; j < 8; ++j) a[j] = b_out[o0 + og * 8 + j];
#pragma unroll 4
    for (int d = 0; d < 64; ++d) {
      float qv = Qt[d][w];
      const f4 w0 = *(const f4*)&Wt[d][og * 8];
      const f4 w1 = *(const f4*)&Wt[d][og * 8 + 4];
      a[0] = fmaf(qv, w0.x, a[0]);
      a[1] = fmaf(qv, w0.y, a[1]);
      a[2] = fmaf(qv, w0.z, a[2]);
      a[3] = fmaf(qv, w0.w, a[3]);
      a[4] = fmaf(qv, w1.x, a[4]);
      a[5] = fmaf(qv, w1.y, a[5]);
      a[6] = fmaf(qv, w1.z, a[6]);
      a[7] = fmaf(qv, w1.w, a[7]);
    }
    float* op = out + (((size_t)b * OUTC + o0 + og * 8) * 32 + h) * 32 + w;
#pragma unroll
    for (int j = 0; j < 8; ++j) op[(size_t)j * 1024] = a[j];
  }
}

extern "C" void kernel_launch(void* const* d_in, const int* in_sizes, int n_in,
                              void* d_out, int out_size, void* d_ws, size_t ws_size,
                              hipStream_t stream) {
  const float* x = (const float*)d_in[0];
  const float* w_in = (const float*)d_in[1];
  const float* b_in = (const float*)d_in[2];
  const float* emb = (const float*)d_in[3];
  const float* w_out = (const float*)d_in[4];
  const float* b_out = (const float*)d_in[5];
  float* out = (float*)d_out;

  __bf16* zbf = (__bf16*)(out + OFF_ZBF);
  __bf16* ebf = (__bf16*)(out + OFF_EBF);
  float* e2h = out + OFF_E2H;
  float* pmv = out + OFF_PMV;
  int* pmi = (int*)(out + OFF_PMI);
  float* idxf = out + OUT_MAIN;  // final indices output (as float), d_out tail

  k_enc<<<1024, 256, 0, stream>>>(x, w_in, b_in, zbf);
  k_prep<<<128, 256, 0, stream>>>(emb, ebf, e2h);
  k_argmin<<<2048, 256, 0, stream>>>(zbf, ebf, e2h, pmv, pmi);
  k_pick<<<64, 256, 0, stream>>>(pmv, pmi, idxf);
  k_dec<<<1024, 256, 0, stream>>>(emb, w_out, b_out, idxf, out);
}